// Round 8
// baseline (252.556 us; speedup 1.0000x reference)
//
#include <hip/hip_runtime.h>

typedef unsigned short u16;
typedef __attribute__((ext_vector_type(8))) short bf16x8;
typedef __attribute__((ext_vector_type(4))) float f32x4;

#define HID 1024
#define BATCH 4096
#define K3 6144   // 3 * 2048 (hi | lo | hi split blocks)
#define NGATE 4096
#define BK 32
#define NT 192    // K3 / BK

// ---------- bf16 helpers ----------
__device__ __forceinline__ u16 f2bf(float f) {
  unsigned int u = __float_as_uint(f);
  u += 0x7FFFu + ((u >> 16) & 1u);   // RNE
  return (u16)(u >> 16);
}
__device__ __forceinline__ float bf2f(u16 h) {
  return __uint_as_float(((unsigned int)h) << 16);
}

__device__ __forceinline__ void load16_to_lds(const void* g, void* l) {
  __builtin_amdgcn_global_load_lds(
      (const __attribute__((address_space(1))) unsigned int*)g,
      (__attribute__((address_space(3))) unsigned int*)l, 16, 0, 0);
}

__device__ __forceinline__ float sigmoid_f(float x) {
  return 1.f / (1.f + __expf(-x));
}
__device__ __forceinline__ float tanh_f(float x) {
  return 1.f - 2.f / (__expf(2.f * x) + 1.f);
}

// ---------- pack activations: Bt[m][k'] = [hi(x|h) | lo(x|h) | hi(x|h)] ----------
__global__ void pack_act(const float* __restrict__ x, const float* __restrict__ h,
                         u16* __restrict__ Bt) {
  size_t idx = (size_t)blockIdx.x * 256 + threadIdx.x;
  int m  = (int)(idx >> 9);
  int kq = (int)(idx & 511) << 2;
  const float* src = (kq < 1024) ? (x + (size_t)m * 1024 + kq)
                                 : (h + (size_t)m * 1024 + (kq - 1024));
  float4 v = *(const float4*)src;
  ushort4 hi, lo;
  hi.x = f2bf(v.x); lo.x = f2bf(v.x - bf2f(hi.x));
  hi.y = f2bf(v.y); lo.y = f2bf(v.y - bf2f(hi.y));
  hi.z = f2bf(v.z); lo.z = f2bf(v.z - bf2f(hi.z));
  hi.w = f2bf(v.w); lo.w = f2bf(v.w - bf2f(hi.w));
  u16* row = Bt + (size_t)m * K3;
  *(ushort4*)(row + kq)        = hi;
  *(ushort4*)(row + 2048 + kq) = lo;
  *(ushort4*)(row + 4096 + kq) = hi;
}

// ---------- pack weights: P[n=4h+g][k'] = [hi(W;U) | hi(W;U) | lo(W;U)] ----------
__global__ void pack_w(const float* __restrict__ Wf, const float* __restrict__ Wi,
                       const float* __restrict__ Wc, const float* __restrict__ Wo,
                       const float* __restrict__ Uf, const float* __restrict__ Ui,
                       const float* __restrict__ Uc, const float* __restrict__ Uo,
                       u16* __restrict__ P) {
  __shared__ float ldsT[32][33];
  int bid = blockIdx.x;
  int mat = bid >> 10;
  int tid = bid & 1023;
  int k0 = (tid >> 5) << 5;
  int h0 = (tid & 31) << 5;
  int g = mat & 3;
  const float* S;
  {
    const float* a = (mat & 1) ? ((mat & 2) ? Wo : Wi) : ((mat & 2) ? Wc : Wf);
    const float* b = (mat & 1) ? ((mat & 2) ? Uo : Ui) : ((mat & 2) ? Uc : Uf);
    S = (mat & 4) ? b : a;
  }
  int kbase = (mat & 4) ? 1024 : 0;

  int t = threadIdx.x;
  {
    int r0 = t >> 5;
    int c  = t & 31;
#pragma unroll
    for (int j = 0; j < 4; ++j)
      ldsT[c][r0 + 8 * j] = S[(size_t)(k0 + r0 + 8 * j) * 1024 + h0 + c];
  }
  __syncthreads();
  {
    int c  = t >> 3;
    int kq = (t & 7) << 2;
    int n  = ((h0 + c) << 2) + g;
    float v0 = ldsT[c][kq + 0], v1 = ldsT[c][kq + 1];
    float v2 = ldsT[c][kq + 2], v3 = ldsT[c][kq + 3];
    ushort4 hi, lo;
    hi.x = f2bf(v0); lo.x = f2bf(v0 - bf2f(hi.x));
    hi.y = f2bf(v1); lo.y = f2bf(v1 - bf2f(hi.y));
    hi.z = f2bf(v2); lo.z = f2bf(v2 - bf2f(hi.z));
    hi.w = f2bf(v3); lo.w = f2bf(v3 - bf2f(hi.w));
    u16* base = P + (size_t)n * K3 + kbase + k0 + kq;
    *(ushort4*)(base)        = hi;
    *(ushort4*)(base + 2048) = hi;
    *(ushort4*)(base + 4096) = lo;
  }
}

// ---------- pack biases ----------
__global__ void pack_bias(const float* __restrict__ bf, const float* __restrict__ bi,
                          const float* __restrict__ bc, const float* __restrict__ bo,
                          float* __restrict__ bcat) {
  int i = blockIdx.x * 256 + threadIdx.x;
  if (i < NGATE) {
    int h = i >> 2, g = i & 3;
    const float* b = (g == 0) ? bf : (g == 1) ? bi : (g == 2) ? bc : bo;
    bcat[i] = b[h];
  }
}

// ---------- fused GEMM + LSTM epilogue ----------
// 256x128 tile, 512 blocks = 2 blocks/CU (the occupancy lever), 8 waves of
// 64x64, BK=32, ring-3 LDS (72 KiB), single sync/tile {lgkmcnt(0)+vmcnt(3)+bar}.
__global__ __launch_bounds__(512, 4) void lstm_gemm(
    const u16* __restrict__ P, const u16* __restrict__ Bt,
    const float* __restrict__ bcat, const float* __restrict__ c_prev,
    float* __restrict__ out) {
  __shared__ __align__(16) u16 As[3][256 * BK];   // 48 KiB
  __shared__ __align__(16) u16 Bs[3][128 * BK];   // 24 KiB

  const int t = threadIdx.x;
  const int w = t >> 6;
  const int l = t & 63;

  // XCD swizzle, m-fast: XCD x gets n_idx {2x,2x+1} (A L2-resident), all m.
  const int bid = blockIdx.x;
  const int swz = ((bid & 7) << 6) + (bid >> 3);   // 512 = 8 XCD * 64
  const int n0 = (swz >> 5) << 8;                  // 16 n-tiles of 256
  const int m0 = (swz & 31) << 7;                  // 32 m-tiles of 128

  const int wn = w & 3;               // 0..3 : wave n-quarter (64 rows of 256)
  const int wm = w >> 2;              // 0..1 : wave m-half   (64 rows of 128)

  // ---- staging: 3 x global_load_lds per K-tile per wave (R2-proven swizzle) ----
  const int srow = t >> 2;                               // 0..127
  const int ssl  = (((t & 3) ^ ((srow >> 1) & 3)) << 3); // swizzled 8-u16 slot
  const u16* gA0 = P  + (size_t)(n0 + srow)       * K3 + ssl;
  const u16* gA1 = P  + (size_t)(n0 + 128 + srow) * K3 + ssl;
  const u16* gB0 = Bt + (size_t)(m0 + srow)       * K3 + ssl;
  const int ldw0 = w << 9;            // wave-uniform LDS dest (u16)
  const int ldw1 = 4096 + (w << 9);

  // ---- fragment read offsets (R2-proven zero-conflict pattern) ----
  const int fr = l & 15;
  const int sl = l >> 4;
  int offA[4], offB[4];
#pragma unroll
  for (int i = 0; i < 4; ++i) {
    int ar = (wn << 6) + i * 16 + fr;          // 0..255
    offA[i] = ar * BK + ((sl ^ ((ar >> 1) & 3)) << 3);
  }
#pragma unroll
  for (int j = 0; j < 4; ++j) {
    int br = (wm << 6) + j * 16 + fr;          // 0..127
    offB[j] = br * BK + ((sl ^ ((br >> 1) & 3)) << 3);
  }

  f32x4 acc[4][4];
#pragma unroll
  for (int i = 0; i < 4; ++i)
#pragma unroll
    for (int j = 0; j < 4; ++j) acc[i][j] = (f32x4){0.f, 0.f, 0.f, 0.f};

  // ---- prologue: stage K-tiles 0,1 into bufs 0,1 ----
#pragma unroll
  for (int pt = 0; pt < 2; ++pt) {
    const int kt = pt * BK;
    load16_to_lds(gA0 + kt, &As[pt][ldw0]);
    load16_to_lds(gA1 + kt, &As[pt][ldw1]);
    load16_to_lds(gB0 + kt, &Bs[pt][ldw0]);
  }

  // ---- main loop: 192 K-tiles, unrolled x3 for static ring indices ----
  for (int t3 = 0; t3 < NT; t3 += 3) {
#pragma unroll
    for (int u = 0; u < 3; ++u) {
      const int tt  = t3 + u;
      const int pfi = tt + 2;
      const int pkt = (pfi < NT ? pfi : NT - 1) * BK;  // clamped tail prefetch
      const int pc  = (u + 2) % 3;

      // single sync point per tile:
      //  lgkmcnt(0): reads of buf[(tt-1)%3] done (stage(tt+2) overwrites it)
      //  vmcnt(3):   stage(tt) landed; stage(tt+1) (3 loads) stays in flight
      asm volatile("s_waitcnt lgkmcnt(0)" ::: "memory");
      asm volatile("s_waitcnt vmcnt(3)" ::: "memory");
      __builtin_amdgcn_s_barrier();
      __builtin_amdgcn_sched_barrier(0);

      // stage tile tt+2 into buf[(tt+2)%3]
      load16_to_lds(gA0 + pkt, &As[pc][ldw0]);
      load16_to_lds(gA1 + pkt, &As[pc][ldw1]);
      load16_to_lds(gB0 + pkt, &Bs[pc][ldw0]);

      // reads + MFMA: barrier-free; compiler interleaves via fine lgkmcnt
      bf16x8 aF[4], bF[4];
#pragma unroll
      for (int i = 0; i < 4; ++i) aF[i] = *(const bf16x8*)&As[u][offA[i]];
#pragma unroll
      for (int j = 0; j < 4; ++j) bF[j] = *(const bf16x8*)&Bs[u][offB[j]];

      __builtin_amdgcn_s_setprio(1);
#pragma unroll
      for (int i = 0; i < 4; ++i)
#pragma unroll
        for (int j = 0; j < 4; ++j)
          acc[i][j] = __builtin_amdgcn_mfma_f32_16x16x32_bf16(aF[i], bF[j], acc[i][j], 0, 0, 0);
      __builtin_amdgcn_s_setprio(0);
    }
  }

  // ---- epilogue: lane regs r=0..3 are gates f,i,c,o of (h, m) ----
  const int n_base = n0 + (wn << 6);
  const int m_base = m0 + (wm << 6);
#pragma unroll
  for (int i = 0; i < 4; ++i) {
    int nf = n_base + i * 16 + ((l >> 4) << 2);
    int hq = nf >> 2;
    float4 b4 = *(const float4*)&bcat[nf];
#pragma unroll
    for (int j = 0; j < 4; ++j) {
      int m = m_base + j * 16 + fr;
      f32x4 a = acc[i][j];
      float ft = sigmoid_f(a[0] + b4.x);
      float it = sigmoid_f(a[1] + b4.y);
      float ct = tanh_f   (a[2] + b4.z);
      float ot = sigmoid_f(a[3] + b4.w);
      float cp = c_prev[(size_t)m * HID + hq];
      float cn = ft * cp + it * ct;
      out[(size_t)m * HID + hq] = ot * tanh_f(cn);
    }
  }
}

extern "C" void kernel_launch(void* const* d_in, const int* in_sizes, int n_in,
                              void* d_out, int out_size, void* d_ws, size_t ws_size,
                              hipStream_t stream) {
  const float* x  = (const float*)d_in[0];
  const float* hp = (const float*)d_in[1];
  const float* cp = (const float*)d_in[2];
  const float* Wf = (const float*)d_in[3];
  const float* Wi = (const float*)d_in[4];
  const float* Wc = (const float*)d_in[5];
  const float* Wo = (const float*)d_in[6];
  const float* Uf = (const float*)d_in[7];
  const float* Ui = (const float*)d_in[8];
  const float* Uc = (const float*)d_in[9];
  const float* Uo = (const float*)d_in[10];
  const float* bf = (const float*)d_in[11];
  const float* bi = (const float*)d_in[12];
  const float* bc = (const float*)d_in[13];
  const float* bo = (const float*)d_in[14];

  const size_t P_BYTES  = (size_t)NGATE * K3 * 2;   // 48 MiB
  const size_t BT_BYTES = (size_t)BATCH * K3 * 2;   // 48 MiB
  u16*   Pw   = (u16*)d_ws;
  u16*   Bt   = (u16*)((char*)d_ws + P_BYTES);
  float* bcat = (float*)((char*)d_ws + P_BYTES + BT_BYTES);
  float* out  = (float*)d_out;

  pack_act <<<dim3(8192), dim3(256), 0, stream>>>(x, hp, Bt);
  pack_w   <<<dim3(8192), dim3(256), 0, stream>>>(Wf, Wi, Wc, Wo, Uf, Ui, Uc, Uo, Pw);
  pack_bias<<<dim3(16),   dim3(256), 0, stream>>>(bf, bi, bc, bo, bcat);
  lstm_gemm<<<dim3(512),  dim3(512), 0, stream>>>(Pw, Bt, bcat, cp, out);
}